// Round 7
// baseline (2335.505 us; speedup 1.0000x reference)
//
#include <hip/hip_runtime.h>

typedef unsigned short ushort_t;
typedef unsigned long long u64_t;
typedef __attribute__((ext_vector_type(8))) short short8;
typedef __attribute__((ext_vector_type(4))) float floatx4;

#define B_ 256
#define T_ 128
#define E_ 300
#define H_ 512
#define NE_ 127   // T-1 reduce events
#define NT_ 255   // 2T-1 transitions
#define SLH_ 260  // slot_h slots per row (256 live + dump + pad)
#define SLC_ 130  // slot_c slots per row (128 live + dump + pad)
#define ZCODE_ 1023
#define PREVF_ 0x10000

__device__ inline ushort_t f2bf(float f){
  unsigned u = __builtin_bit_cast(unsigned, f);
  unsigned r = u + 0x7FFFu + ((u >> 16) & 1u);
  return (ushort_t)(r >> 16);
}
__device__ inline float bf2f(ushort_t h){
  unsigned u = ((unsigned)h) << 16;
  return __builtin_bit_cast(float, u);
}
__device__ inline float sigm(float x){ return 1.0f / (1.0f + __expf(-x)); }

// Agent-scope relaxed (sc0 sc1) ops: bypass stale L1/L2, served by L3.
__device__ inline short8 load_a_coh(const ushort_t* p){
  union { u64_t q[2]; short8 v; } u;
  u.q[0] = __hip_atomic_load((u64_t*)p,       __ATOMIC_RELAXED, __HIP_MEMORY_SCOPE_AGENT);
  u.q[1] = __hip_atomic_load((u64_t*)(p + 4), __ATOMIC_RELAXED, __HIP_MEMORY_SCOPE_AGENT);
  return u.v;
}
__device__ inline void store_h_coh(ushort_t* p, ushort_t v){
  __hip_atomic_store(p, v, __ATOMIC_RELAXED, __HIP_MEMORY_SCOPE_AGENT);
}

// ---------------------------------------------------------------------------
// x (fp32, rows of 300) -> xb (bf16, rows padded to 320, pad = 0)
// ---------------------------------------------------------------------------
__global__ __launch_bounds__(256) void xcast_kernel(const float* __restrict__ x,
    ushort_t* __restrict__ xb){
  int t = blockIdx.x * 256 + threadIdx.x;
  if (t >= (B_ * T_) * 40) return;
  int row = t / 40, k8 = (t % 40) * 8;
  const float* src = x + (size_t)row * E_;
  short8 v;
  #pragma unroll
  for (int j = 0; j < 8; ++j){
    int k = k8 + j;
    v[j] = (k < E_) ? (short)f2bf(src[k]) : (short)0;
  }
  *(short8*)(xb + (size_t)row * 320 + k8) = v;
}

// ---------------------------------------------------------------------------
// Pack a KxN row-major fp32 weight into MFMA B-fragment order (bf16).
// ---------------------------------------------------------------------------
__global__ __launch_bounds__(256) void pack_w_kernel(const float* __restrict__ W,
    ushort_t* __restrict__ dst, int K, int N, int NS, int total){
  int t = blockIdx.x * 256 + threadIdx.x;
  if (t >= total) return;
  int L = t & 63;
  int s = (t >> 6) % NS;
  int ct = t / (64 * NS);
  int n = ct * 16 + (L & 15);
  int kbase = s * 32 + ((L >> 4) << 3);
  short8 pack;
  #pragma unroll
  for (int j = 0; j < 8; ++j){
    int k = kbase + j;
    pack[j] = (k < K) ? (short)f2bf(W[(size_t)k * N + n]) : (short)0;
  }
  *(short8*)(dst + (size_t)t * 8) = pack;
}

// ---------------------------------------------------------------------------
// Stack machine with SLOT-RECYCLED storage. Codes (low 10 bits):
//   [0,128) leaf | [256,512) node at phys h-slot (c-slot = phys>>1) | 1023 zeros
// PREVF_: child is the previous event's node (c register-carried).
// Phys h-slot = stackpos*2 + toggle -> intra-event WAR-free; cross-event WAR
// covered by the chain's unconditional top-of-event flag wait.
// ---------------------------------------------------------------------------
__global__ void sched_kernel(const int* __restrict__ trans, int* __restrict__ lsel,
    int* __restrict__ rsel, int* __restrict__ wph, int* __restrict__ rootsel){
  __shared__ int stk[32 * 128];    // value code
  __shared__ int stkid[32 * 128];  // node id (T_+e) or leaf idx
  int tid = threadIdx.x;           // 0..31
  int b0 = blockIdx.x * 32;
  int b = b0 + tid;
  for (int i = 0; i < 128; ++i){ stk[tid * 128 + i] = ZCODE_; stkid[tid * 128 + i] = -1; }
  u64_t tog0 = 0, tog1 = 0;
  int sp = 0, bp = T_, e = 0;
  for (int t = 0; t < NT_; ++t){
    int tr = trans[t * B_ + b];
    if (tr == 0){
      int pos = sp; if (pos < 0) pos = 0; if (pos > 127) pos = 127;
      stk[tid * 128 + pos] = bp - 1;
      stkid[tid * 128 + pos] = bp - 1;
      sp += 1; bp -= 1;
    } else {
      int i2 = sp - 2; if (i2 < 0) i2 = 0; if (i2 > 127) i2 = 127;
      int i1 = sp - 1; if (i1 < 0) i1 = 0; if (i1 > 127) i1 = 127;
      if (e < NE_){
        int lc = stk[tid * 128 + i2], rc = stk[tid * 128 + i1];
        int lid = stkid[tid * 128 + i2], rid = stkid[tid * 128 + i1];
        int previd = T_ + e - 1;
        lsel[e * B_ + b] = lc | ((e > 0 && lid == previd) ? PREVF_ : 0);
        rsel[e * B_ + b] = rc | ((e > 0 && rid == previd) ? PREVF_ : 0);
        int pos = i2;
        unsigned ob;
        if (pos < 64){ ob = (unsigned)((tog0 >> pos) & 1); tog0 ^= (1ull << pos); }
        else         { ob = (unsigned)((tog1 >> (pos - 64)) & 1); tog1 ^= (1ull << (pos - 64)); }
        int phys = pos * 2 + (int)(ob ^ 1u);
        wph[e * B_ + b] = phys;
        stk[tid * 128 + pos] = 256 + phys;
        stkid[tid * 128 + pos] = T_ + e;
      }
      e += 1; sp -= 1;
    }
  }
  for (int k = e; k < NE_; ++k){
    lsel[k * B_ + b] = ZCODE_; rsel[k * B_ + b] = ZCODE_;
    wph[k * B_ + b] = 256;     // dump slot — never aliases live slots
  }
  int ip = sp - 1; if (ip < 0) ip = 0; if (ip > 127) ip = 127;
  rootsel[b] = stk[tid * 128 + ip];
}

// ---------------------------------------------------------------------------
// Leaf phase from pre-cast bf16 x (padded K=320). WG = 4 waves x 16 rows =
// 64 rows, 128 cols (8 col-tiles) for both weights. Grid (512, 4).
// ---------------------------------------------------------------------------
__global__ __launch_bounds__(256) void leaf_kernel(const ushort_t* __restrict__ xb,
    const ushort_t* __restrict__ WpP, const ushort_t* __restrict__ WgP,
    const float* __restrict__ b_proj, const float* __restrict__ b_gate,
    ushort_t* __restrict__ leaf_h, ushort_t* __restrict__ leaf_c){
  int wave = threadIdx.x >> 6, lane = threadIdx.x & 63;
  int r0 = blockIdx.x * 64 + wave * 16;
  int cbase = blockIdx.y * 8;
  int arow = r0 + (lane & 15);
  int klane = (lane >> 4) << 3;
  const ushort_t* xrow = xb + (size_t)arow * 320;
  floatx4 accP[8], accG[8];
  #pragma unroll
  for (int i = 0; i < 8; ++i){ accP[i] = (floatx4){0,0,0,0}; accG[i] = (floatx4){0,0,0,0}; }
  #pragma unroll
  for (int s = 0; s < 10; ++s){
    short8 a = *(const short8*)(xrow + s * 32 + klane);
    #pragma unroll
    for (int cc = 0; cc < 8; ++cc){
      short8 bp = *(const short8*)(WpP + (((size_t)(cbase + cc) * 10 + s) * 64 + lane) * 8);
      accP[cc] = __builtin_amdgcn_mfma_f32_16x16x32_bf16(a, bp, accP[cc], 0, 0, 0);
      short8 bg = *(const short8*)(WgP + (((size_t)(cbase + cc) * 10 + s) * 64 + lane) * 8);
      accG[cc] = __builtin_amdgcn_mfma_f32_16x16x32_bf16(a, bg, accG[cc], 0, 0, 0);
    }
  }
  int rbase = r0 + ((lane >> 4) << 2);
  #pragma unroll
  for (int cc = 0; cc < 8; ++cc){
    int col = (cbase + cc) * 16 + (lane & 15);
    float bp = b_proj[col], bg = b_gate[col];
    #pragma unroll
    for (int r = 0; r < 4; ++r){
      int row = rbase + r;
      float cv = accP[cc][r] + bp;
      float hv = sigm(accG[cc][r] + bg) * tanhf(cv);
      size_t o = (size_t)row * H_ + col;
      leaf_c[o] = f2bf(cv);
      leaf_h[o] = f2bf(hv);
    }
  }
}

// ---------------------------------------------------------------------------
// Persistent chain, R7. Layout: cth = bid>>3, rg = bid&7, so under the
// observed chunked bid->XCD mapping each XCD hosts only 4 cth W-slices
// (656 KB -> L2-resident; R6's contiguous groups put all 5.24 MB of W on
// every XCD -> per-event thrash = the 2.6 MB/event FETCH signature).
// Sync: per-WG flag words (flags[rg][cth] = events completed), poll = one
// 32-lane coherent vector load + __all — no atomic-RMW serialization.
// All waves wait flags >= e at top of event (also closes slot WAR; the phys
// toggle covers the intra-event case). Per event, W fragments (40 short8)
// are loaded into registers BEFORE the wait (asm pin) so W latency hides
// behind the inter-event wait; leaf-child A/c loads also issue pre-wait.
// LDS partial buffer double-buffered by event parity -> single syncthreads
// per event (partials -> wave 0).
// ---------------------------------------------------------------------------
__global__ __launch_bounds__(256, 1) void chain_kernel(
    const ushort_t* __restrict__ WrP, const float* __restrict__ b_reduce,
    const ushort_t* __restrict__ leaf_h, const ushort_t* __restrict__ leaf_c,
    ushort_t* __restrict__ slot_h, float* __restrict__ slot_c,
    const int* __restrict__ lsel, const int* __restrict__ rsel,
    const int* __restrict__ wph, const ushort_t* __restrict__ zbuf,
    unsigned* __restrict__ gflags){
  __shared__ float part[2][3][2][64][24];   // [parity][kq-1][rt][lane][g*4+r]
  const int bid  = blockIdx.x;
  const int cth  = bid >> 3;
  const int rg   = bid & 7;
  const int kq   = threadIdx.x >> 6;     // wave = K-quarter
  const int lane = threadIdx.x & 63;
  const int m16  = lane & 15;
  const int klane = (lane >> 4) << 3;
  const int colh = cth * 16 + m16;
  const int row0 = rg * 32;
  unsigned* flagbase = gflags + rg * 64; // 256B-strided per-group flag arrays
  float bias[5];
  if (kq == 0){
    #pragma unroll
    for (int g = 0; g < 5; ++g) bias[g] = b_reduce[g * H_ + colh];
  }
  const int* ssel = (kq < 2) ? lsel : rsel;    // kq 0,1 = left child half
  const int kcolbase = (kq & 1) * 256;         // col offset within child h
  float creg[2][4];                            // c written last event (wave 0)
  #pragma unroll
  for (int rt = 0; rt < 2; ++rt)
    #pragma unroll
    for (int r = 0; r < 4; ++r) creg[rt][r] = 0.0f;

  #pragma unroll 1
  for (int e = 0; e < NE_; ++e){
    const int par = e & 1;

    // ---- child codes (small cached arrays) ----
    int code[2];
    const ushort_t* leafp[2];
    #pragma unroll
    for (int rt = 0; rt < 2; ++rt){
      int row = row0 + rt * 16 + m16;
      code[rt] = ssel[e * B_ + row] & 0x3FF;
      leafp[rt] = (code[rt] < 128) ? leaf_h + ((size_t)row * T_ + code[rt]) * H_ + kcolbase
                                   : zbuf;
    }

    // ---- W fragments: load + pin in regs BEFORE the wait ----
    short8 Wreg[5][8];
    #pragma unroll
    for (int g = 0; g < 5; ++g)
      #pragma unroll
      for (int s = 0; s < 8; ++s)
        Wreg[g][s] = *(const short8*)(WrP + (((size_t)(g * 32 + cth) * 32 + kq * 8 + s) * 64 + lane) * 8);
    #pragma unroll
    for (int g = 0; g < 5; ++g)
      asm volatile("" : "+v"(Wreg[g][0]), "+v"(Wreg[g][1]), "+v"(Wreg[g][2]),
                        "+v"(Wreg[g][3]), "+v"(Wreg[g][4]), "+v"(Wreg[g][5]),
                        "+v"(Wreg[g][6]), "+v"(Wreg[g][7]));

    // ---- leaf-child A prefetch (independent of previous event) ----
    short8 Ab[2][8];
    #pragma unroll
    for (int rt = 0; rt < 2; ++rt){
      if (code[rt] < 256 || code[rt] >= 512){   // leaf or zeros: plain cached
        #pragma unroll
        for (int s = 0; s < 8; ++s) Ab[rt][s] = *(const short8*)(leafp[rt] + s * 32 + klane);
      }
    }

    // ---- wave 0: prefetch leaf c operands ----
    float cl[2][4], cr[2][4];
    int lsv[2][4], rsv[2][4];
    if (kq == 0){
      #pragma unroll
      for (int rt = 0; rt < 2; ++rt){
        int rbase = row0 + rt * 16 + ((lane >> 4) << 2);
        #pragma unroll
        for (int r = 0; r < 4; ++r){
          const int bb = rbase + r;
          const int ls = lsel[e * B_ + bb], rs = rsel[e * B_ + bb];
          lsv[rt][r] = ls; rsv[rt][r] = rs;
          int lc = ls & 0x3FF, rc = rs & 0x3FF;
          cl[rt][r] = (!(ls & PREVF_) && lc < 128) ? bf2f(leaf_c[((size_t)bb * T_ + lc) * H_ + colh]) : 0.0f;
          cr[rt][r] = (!(rs & PREVF_) && rc < 128) ? bf2f(leaf_c[((size_t)bb * T_ + rc) * H_ + colh]) : 0.0f;
        }
      }
    }

    // ---- wait: all group members completed event e-1 ----
    if (e > 0){
      const unsigned tgt = (unsigned)e;
      unsigned* fp = flagbase + (lane & 31);
      for (;;){
        unsigned v = __hip_atomic_load(fp, __ATOMIC_RELAXED, __HIP_MEMORY_SCOPE_AGENT);
        if (__all(v >= tgt)) break;
        __builtin_amdgcn_s_sleep(0);
      }
    }

    // ---- node-child A loads (coherent, L3) ----
    #pragma unroll
    for (int rt = 0; rt < 2; ++rt){
      if (code[rt] >= 256 && code[rt] < 512){
        int row = row0 + rt * 16 + m16;
        const ushort_t* p = slot_h + ((size_t)row * SLH_ + (code[rt] - 256)) * H_ + kcolbase;
        #pragma unroll
        for (int s = 0; s < 8; ++s) Ab[rt][s] = load_a_coh(p + s * 32 + klane);
      }
    }

    // ---- wave 0: remaining c operands (PREVF regs / WG-private slot_c) ----
    if (kq == 0){
      #pragma unroll
      for (int rt = 0; rt < 2; ++rt){
        int rbase = row0 + rt * 16 + ((lane >> 4) << 2);
        #pragma unroll
        for (int r = 0; r < 4; ++r){
          const int bb = rbase + r;
          const int ls = lsv[rt][r], rs = rsv[rt][r];
          int lc = ls & 0x3FF, rc = rs & 0x3FF;
          if (ls & PREVF_) cl[rt][r] = creg[rt][r];
          else if (lc >= 256 && lc < 512) cl[rt][r] = slot_c[((size_t)bb * SLC_ + ((lc - 256) >> 1)) * H_ + colh];
          if (rs & PREVF_) cr[rt][r] = creg[rt][r];
          else if (rc >= 256 && rc < 512) cr[rt][r] = slot_c[((size_t)bb * SLC_ + ((rc - 256) >> 1)) * H_ + colh];
        }
      }
    }

    // ---- MFMA: B from pinned registers ----
    floatx4 acc[2][5];
    #pragma unroll
    for (int rt = 0; rt < 2; ++rt)
      #pragma unroll
      for (int g = 0; g < 5; ++g) acc[rt][g] = (floatx4){0,0,0,0};
    #pragma unroll
    for (int s = 0; s < 8; ++s){
      #pragma unroll
      for (int g = 0; g < 5; ++g){
        acc[0][g] = __builtin_amdgcn_mfma_f32_16x16x32_bf16(Ab[0][s], Wreg[g][s], acc[0][g], 0, 0, 0);
        acc[1][g] = __builtin_amdgcn_mfma_f32_16x16x32_bf16(Ab[1][s], Wreg[g][s], acc[1][g], 0, 0, 0);
      }
    }
    if (kq != 0){
      #pragma unroll
      for (int rt = 0; rt < 2; ++rt)
        #pragma unroll
        for (int g = 0; g < 5; ++g)
          *(floatx4*)&part[par][kq - 1][rt][lane][g * 4] = acc[rt][g];
    }
    __syncthreads();   // partials of event e visible to wave 0
    if (kq == 0){
      #pragma unroll
      for (int rt = 0; rt < 2; ++rt)
        #pragma unroll
        for (int g = 0; g < 5; ++g){
          floatx4 p0 = *(floatx4*)&part[par][0][rt][lane][g * 4];
          floatx4 p1 = *(floatx4*)&part[par][1][rt][lane][g * 4];
          floatx4 p2 = *(floatx4*)&part[par][2][rt][lane][g * 4];
          #pragma unroll
          for (int r = 0; r < 4; ++r) acc[rt][g][r] += p0[r] + p1[r] + p2[r];
        }
      #pragma unroll
      for (int rt = 0; rt < 2; ++rt){
        int rbase = row0 + rt * 16 + ((lane >> 4) << 2);
        #pragma unroll
        for (int r = 0; r < 4; ++r){
          const int bb = rbase + r;
          float cn = sigm(acc[rt][1][r] + bias[1]) * cl[rt][r]
                   + sigm(acc[rt][2][r] + bias[2]) * cr[rt][r]
                   + sigm(acc[rt][0][r] + bias[0]) * tanhf(acc[rt][3][r] + bias[3]);
          float hn = sigm(acc[rt][4][r] + bias[4]) * tanhf(cn);
          creg[rt][r] = cn;
          const int w = wph[e * B_ + bb];
          slot_c[((size_t)bb * SLC_ + (w >> 1)) * H_ + colh] = cn;   // WG-private
          store_h_coh(slot_h + ((size_t)bb * SLH_ + w) * H_ + colh, f2bf(hn));
        }
      }
      asm volatile("s_waitcnt vmcnt(0)" ::: "memory");   // drain h stores
      if (threadIdx.x == 0)
        __hip_atomic_store(flagbase + cth, (unsigned)(e + 1),
                           __ATOMIC_RELAXED, __HIP_MEMORY_SCOPE_AGENT);
    }
  }
}

// Final: out[b][j] = h of root (leaf / node slot / zeros). Covers every row.
__global__ __launch_bounds__(256) void final_kernel(const int* __restrict__ rootsel,
    const ushort_t* __restrict__ leaf_h, const ushort_t* __restrict__ slot_h,
    float* __restrict__ out){
  int i = blockIdx.x * 256 + threadIdx.x;
  if (i >= B_ * H_) return;
  int b = i >> 9, j = i & (H_ - 1);
  int code = rootsel[b] & 0x3FF;
  float v = 0.0f;
  if (code < 128)      v = bf2f(leaf_h[((size_t)b * T_ + code) * H_ + j]);
  else if (code < 512) v = bf2f(slot_h[((size_t)b * SLH_ + (code - 256)) * H_ + j]);
  out[i] = v;
}

extern "C" void kernel_launch(void* const* d_in, const int* in_sizes, int n_in,
                              void* d_out, int out_size, void* d_ws, size_t ws_size,
                              hipStream_t stream){
  const float* x        = (const float*)d_in[0];
  const float* W_proj   = (const float*)d_in[1];
  const float* b_proj   = (const float*)d_in[2];
  const float* W_gate   = (const float*)d_in[3];
  const float* b_gate   = (const float*)d_in[4];
  const float* W_reduce = (const float*)d_in[5];
  const float* b_reduce = (const float*)d_in[6];
  const int*   trans    = (const int*)d_in[7];
  float* out = (float*)d_out;

  char* ws = (char*)d_ws;
  size_t o = 0;
  ushort_t* WpP    = (ushort_t*)(ws + o); o += (size_t)32*10*64*8*2;    // 0.33 MB
  ushort_t* WgP    = (ushort_t*)(ws + o); o += (size_t)32*10*64*8*2;
  ushort_t* WrP    = (ushort_t*)(ws + o); o += (size_t)160*32*64*8*2;   // 5.24 MB
  ushort_t* leaf_h = (ushort_t*)(ws + o); o += (size_t)B_*T_*H_*2;      // 33.5 MB
  ushort_t* leaf_c = (ushort_t*)(ws + o); o += (size_t)B_*T_*H_*2;      // 33.5 MB
  ushort_t* slot_h = (ushort_t*)(ws + o); o += (size_t)B_*SLH_*H_*2;    // 68.2 MB
  float*    slot_c = (float*)(ws + o);    o += (size_t)B_*SLC_*H_*4;    // 68.2 MB
  int* lsel    = (int*)(ws + o); o += (size_t)NE_*B_*4;
  int* rsel    = (int*)(ws + o); o += (size_t)NE_*B_*4;
  int* wph     = (int*)(ws + o); o += (size_t)NE_*B_*4;
  int* rootsel = (int*)(ws + o); o += (size_t)B_*4;
  unsigned* gflags = (unsigned*)(ws + o); o += 8 * 64 * 4;  // flags[rg][cth], 256B/group
  ushort_t* zbuf = (ushort_t*)(ws + o); o += 2048;
  // xb (bf16 x, padded to K=320, 21 MB) overlays slot_c: xb is only read
  // before chain_kernel; slot_c is only accessed during/after it.
  ushort_t* xb = (ushort_t*)slot_c;
  (void)ws_size; (void)in_sizes; (void)n_in; (void)out_size;

  hipMemsetAsync(gflags, 0, 8 * 64 * 4, stream);
  hipMemsetAsync(zbuf, 0, 2048, stream);
  xcast_kernel<<<((B_*T_)*40 + 255)/256, 256, 0, stream>>>(x, xb);
  pack_w_kernel<<<(32*10*64 + 255)/256, 256, 0, stream>>>(W_proj, WpP, 300, 512, 10, 32*10*64);
  pack_w_kernel<<<(32*10*64 + 255)/256, 256, 0, stream>>>(W_gate, WgP, 300, 512, 10, 32*10*64);
  pack_w_kernel<<<(160*32*64 + 255)/256, 256, 0, stream>>>(W_reduce, WrP, 1024, 2560, 32, 160*32*64);
  sched_kernel<<<8, 32, 0, stream>>>(trans, lsel, rsel, wph, rootsel);
  leaf_kernel<<<dim3(512, 4), 256, 0, stream>>>(xb, WpP, WgP, b_proj, b_gate, leaf_h, leaf_c);
  chain_kernel<<<256, 256, 0, stream>>>(WrP, b_reduce, leaf_h, leaf_c, slot_h, slot_c,
                                        lsel, rsel, wph, zbuf, gflags);
  final_kernel<<<(B_*H_ + 255)/256, 256, 0, stream>>>(rootsel, leaf_h, slot_h, out);
}

// Round 8
// 2022.932 us; speedup vs baseline: 1.1545x; 1.1545x over previous
//
#include <hip/hip_runtime.h>

typedef unsigned short ushort_t;
typedef unsigned long long u64_t;
typedef __attribute__((ext_vector_type(8))) short short8;
typedef __attribute__((ext_vector_type(4))) float floatx4;

#define B_ 256
#define T_ 128
#define E_ 300
#define H_ 512
#define NE_ 127   // T-1 reduce events
#define NT_ 255   // 2T-1 transitions
#define SLH_ 260  // slot_h slots per row (256 live + dump + pad)
#define SLC_ 130  // slot_c slots per row (128 live + dump + pad)
#define ZCODE_ 1023
#define PREVF_ 0x10000

__device__ inline ushort_t f2bf(float f){
  unsigned u = __builtin_bit_cast(unsigned, f);
  unsigned r = u + 0x7FFFu + ((u >> 16) & 1u);
  return (ushort_t)(r >> 16);
}
__device__ inline float bf2f(ushort_t h){
  unsigned u = ((unsigned)h) << 16;
  return __builtin_bit_cast(float, u);
}
__device__ inline float sigm(float x){ return 1.0f / (1.0f + __expf(-x)); }

// Agent-scope relaxed (sc0 sc1) ops: bypass stale L1/L2, served by L3.
__device__ inline short8 load_a_coh(const ushort_t* p){
  union { u64_t q[2]; short8 v; } u;
  u.q[0] = __hip_atomic_load((u64_t*)p,       __ATOMIC_RELAXED, __HIP_MEMORY_SCOPE_AGENT);
  u.q[1] = __hip_atomic_load((u64_t*)(p + 4), __ATOMIC_RELAXED, __HIP_MEMORY_SCOPE_AGENT);
  return u.v;
}
__device__ inline void store_h_coh(ushort_t* p, ushort_t v){
  __hip_atomic_store(p, v, __ATOMIC_RELAXED, __HIP_MEMORY_SCOPE_AGENT);
}

// ---------------------------------------------------------------------------
// x (fp32, rows of 300) -> xb (bf16, rows padded to 320, pad = 0)
// ---------------------------------------------------------------------------
__global__ __launch_bounds__(256) void xcast_kernel(const float* __restrict__ x,
    ushort_t* __restrict__ xb){
  int t = blockIdx.x * 256 + threadIdx.x;
  if (t >= (B_ * T_) * 40) return;
  int row = t / 40, k8 = (t % 40) * 8;
  const float* src = x + (size_t)row * E_;
  short8 v;
  #pragma unroll
  for (int j = 0; j < 8; ++j){
    int k = k8 + j;
    v[j] = (k < E_) ? (short)f2bf(src[k]) : (short)0;
  }
  *(short8*)(xb + (size_t)row * 320 + k8) = v;
}

// ---------------------------------------------------------------------------
// Pack a KxN row-major fp32 weight into MFMA B-fragment order (bf16).
// ---------------------------------------------------------------------------
__global__ __launch_bounds__(256) void pack_w_kernel(const float* __restrict__ W,
    ushort_t* __restrict__ dst, int K, int N, int NS, int total){
  int t = blockIdx.x * 256 + threadIdx.x;
  if (t >= total) return;
  int L = t & 63;
  int s = (t >> 6) % NS;
  int ct = t / (64 * NS);
  int n = ct * 16 + (L & 15);
  int kbase = s * 32 + ((L >> 4) << 3);
  short8 pack;
  #pragma unroll
  for (int j = 0; j < 8; ++j){
    int k = kbase + j;
    pack[j] = (k < K) ? (short)f2bf(W[(size_t)k * N + n]) : (short)0;
  }
  *(short8*)(dst + (size_t)t * 8) = pack;
}

// ---------------------------------------------------------------------------
// Stack machine with SLOT-RECYCLED storage. Codes (low 10 bits):
//   [0,128) leaf | [256,512) node at phys h-slot (c-slot = phys>>1) | 1023 zeros
// PREVF_: child is the previous event's node (c register-carried).
// ---------------------------------------------------------------------------
__global__ void sched_kernel(const int* __restrict__ trans, int* __restrict__ lsel,
    int* __restrict__ rsel, int* __restrict__ wph, int* __restrict__ rootsel){
  __shared__ int stk[32 * 128];    // value code
  __shared__ int stkid[32 * 128];  // node id (T_+e) or leaf idx
  int tid = threadIdx.x;           // 0..31
  int b0 = blockIdx.x * 32;
  int b = b0 + tid;
  for (int i = 0; i < 128; ++i){ stk[tid * 128 + i] = ZCODE_; stkid[tid * 128 + i] = -1; }
  u64_t tog0 = 0, tog1 = 0;
  int sp = 0, bp = T_, e = 0;
  for (int t = 0; t < NT_; ++t){
    int tr = trans[t * B_ + b];
    if (tr == 0){
      int pos = sp; if (pos < 0) pos = 0; if (pos > 127) pos = 127;
      stk[tid * 128 + pos] = bp - 1;
      stkid[tid * 128 + pos] = bp - 1;
      sp += 1; bp -= 1;
    } else {
      int i2 = sp - 2; if (i2 < 0) i2 = 0; if (i2 > 127) i2 = 127;
      int i1 = sp - 1; if (i1 < 0) i1 = 0; if (i1 > 127) i1 = 127;
      if (e < NE_){
        int lc = stk[tid * 128 + i2], rc = stk[tid * 128 + i1];
        int lid = stkid[tid * 128 + i2], rid = stkid[tid * 128 + i1];
        int previd = T_ + e - 1;
        lsel[e * B_ + b] = lc | ((e > 0 && lid == previd) ? PREVF_ : 0);
        rsel[e * B_ + b] = rc | ((e > 0 && rid == previd) ? PREVF_ : 0);
        int pos = i2;
        unsigned ob;
        if (pos < 64){ ob = (unsigned)((tog0 >> pos) & 1); tog0 ^= (1ull << pos); }
        else         { ob = (unsigned)((tog1 >> (pos - 64)) & 1); tog1 ^= (1ull << (pos - 64)); }
        int phys = pos * 2 + (int)(ob ^ 1u);
        wph[e * B_ + b] = phys;
        stk[tid * 128 + pos] = 256 + phys;
        stkid[tid * 128 + pos] = T_ + e;
      }
      e += 1; sp -= 1;
    }
  }
  for (int k = e; k < NE_; ++k){
    lsel[k * B_ + b] = ZCODE_; rsel[k * B_ + b] = ZCODE_;
    wph[k * B_ + b] = 256;     // dump slot — never aliases live slots
  }
  int ip = sp - 1; if (ip < 0) ip = 0; if (ip > 127) ip = 127;
  rootsel[b] = stk[tid * 128 + ip];
}

// ---------------------------------------------------------------------------
// Leaf phase from pre-cast bf16 x (padded K=320). WG = 4 waves x 16 rows =
// 64 rows, 128 cols (8 col-tiles) for both weights. Grid (512, 4).
// ---------------------------------------------------------------------------
__global__ __launch_bounds__(256) void leaf_kernel(const ushort_t* __restrict__ xb,
    const ushort_t* __restrict__ WpP, const ushort_t* __restrict__ WgP,
    const float* __restrict__ b_proj, const float* __restrict__ b_gate,
    ushort_t* __restrict__ leaf_h, ushort_t* __restrict__ leaf_c){
  int wave = threadIdx.x >> 6, lane = threadIdx.x & 63;
  int r0 = blockIdx.x * 64 + wave * 16;
  int cbase = blockIdx.y * 8;
  int arow = r0 + (lane & 15);
  int klane = (lane >> 4) << 3;
  const ushort_t* xrow = xb + (size_t)arow * 320;
  floatx4 accP[8], accG[8];
  #pragma unroll
  for (int i = 0; i < 8; ++i){ accP[i] = (floatx4){0,0,0,0}; accG[i] = (floatx4){0,0,0,0}; }
  #pragma unroll
  for (int s = 0; s < 10; ++s){
    short8 a = *(const short8*)(xrow + s * 32 + klane);
    #pragma unroll
    for (int cc = 0; cc < 8; ++cc){
      short8 bp = *(const short8*)(WpP + (((size_t)(cbase + cc) * 10 + s) * 64 + lane) * 8);
      accP[cc] = __builtin_amdgcn_mfma_f32_16x16x32_bf16(a, bp, accP[cc], 0, 0, 0);
      short8 bg = *(const short8*)(WgP + (((size_t)(cbase + cc) * 10 + s) * 64 + lane) * 8);
      accG[cc] = __builtin_amdgcn_mfma_f32_16x16x32_bf16(a, bg, accG[cc], 0, 0, 0);
    }
  }
  int rbase = r0 + ((lane >> 4) << 2);
  #pragma unroll
  for (int cc = 0; cc < 8; ++cc){
    int col = (cbase + cc) * 16 + (lane & 15);
    float bp = b_proj[col], bg = b_gate[col];
    #pragma unroll
    for (int r = 0; r < 4; ++r){
      int row = rbase + r;
      float cv = accP[cc][r] + bp;
      float hv = sigm(accG[cc][r] + bg) * tanhf(cv);
      size_t o = (size_t)row * H_ + col;
      leaf_c[o] = f2bf(cv);
      leaf_h[o] = f2bf(hv);
    }
  }
}

// ---------------------------------------------------------------------------
// Persistent chain, R8. Identical dataflow to R7 except the group barrier:
// flags[rg][cth] now live on 32 DISTINCT 128B cache lines (stride 32 dwords).
// R3-R7 put all 32 arrivals in ONE line -> ~32 serialized L3 line ops
// (~500-700 cyc each) = the invariant ~15 us/event. Distinct lines make the
// 32 producer stores parallel across L3 banks; the consumer polls with one
// 32-lane gather (pipelined). Only wave kq0 polls; waves 1-3 are released
// by the S1 __syncthreads (4x fewer pollers, no poll storm on the lines).
// LDS partials: [kq][rt][g][lane] floatx4, contiguous 16B/lane ->
// conflict-free (R7's stride-24 layout cost 1.17e7 conflict cycles);
// no parity needed with the two-barrier structure (partial writes of event
// e+1 happen after S1(e+1), which wave 0 only reaches after reading event
// e's partials).
// ---------------------------------------------------------------------------
__global__ __launch_bounds__(256, 1) void chain_kernel(
    const ushort_t* __restrict__ WrP, const float* __restrict__ b_reduce,
    const ushort_t* __restrict__ leaf_h, const ushort_t* __restrict__ leaf_c,
    ushort_t* __restrict__ slot_h, float* __restrict__ slot_c,
    const int* __restrict__ lsel, const int* __restrict__ rsel,
    const int* __restrict__ wph, const ushort_t* __restrict__ zbuf,
    unsigned* __restrict__ gflags){
  __shared__ floatx4 part[3][2][5][64];   // [kq-1][rt][g][lane] — conflict-free
  const int bid  = blockIdx.x;
  const int cth  = bid >> 3;
  const int rg   = bid & 7;
  const int kq   = threadIdx.x >> 6;     // wave = K-quarter
  const int lane = threadIdx.x & 63;
  const int m16  = lane & 15;
  const int klane = (lane >> 4) << 3;
  const int colh = cth * 16 + m16;
  const int row0 = rg * 32;
  float bias[5];
  if (kq == 0){
    #pragma unroll
    for (int g = 0; g < 5; ++g) bias[g] = b_reduce[g * H_ + colh];
  }
  const int* ssel = (kq < 2) ? lsel : rsel;    // kq 0,1 = left child half
  const int kcolbase = (kq & 1) * 256;         // col offset within child h
  unsigned* myflag  = gflags + ((unsigned)(rg * 32 + cth) << 5);       // 128B stride
  unsigned* pollptr = gflags + ((unsigned)(rg * 32 + (lane & 31)) << 5);
  float creg[2][4];                            // c written last event (wave 0)
  #pragma unroll
  for (int rt = 0; rt < 2; ++rt)
    #pragma unroll
    for (int r = 0; r < 4; ++r) creg[rt][r] = 0.0f;

  #pragma unroll 1
  for (int e = 0; e < NE_; ++e){
    // ---- child codes ----
    int code[2];
    const ushort_t* leafp[2];
    #pragma unroll
    for (int rt = 0; rt < 2; ++rt){
      int row = row0 + rt * 16 + m16;
      code[rt] = ssel[e * B_ + row] & 0x3FF;
      leafp[rt] = (code[rt] < 128) ? leaf_h + ((size_t)row * T_ + code[rt]) * H_ + kcolbase
                                   : zbuf;
    }

    // ---- W fragments: load + pin in regs BEFORE the wait (L2-hit) ----
    short8 Wreg[5][8];
    #pragma unroll
    for (int g = 0; g < 5; ++g)
      #pragma unroll
      for (int s = 0; s < 8; ++s)
        Wreg[g][s] = *(const short8*)(WrP + (((size_t)(g * 32 + cth) * 32 + kq * 8 + s) * 64 + lane) * 8);
    #pragma unroll
    for (int g = 0; g < 5; ++g)
      asm volatile("" : "+v"(Wreg[g][0]), "+v"(Wreg[g][1]), "+v"(Wreg[g][2]),
                        "+v"(Wreg[g][3]), "+v"(Wreg[g][4]), "+v"(Wreg[g][5]),
                        "+v"(Wreg[g][6]), "+v"(Wreg[g][7]));

    // ---- leaf-child A prefetch (independent of previous event) ----
    short8 Ab[2][8];
    #pragma unroll
    for (int rt = 0; rt < 2; ++rt){
      if (code[rt] < 256 || code[rt] >= 512){
        #pragma unroll
        for (int s = 0; s < 8; ++s) Ab[rt][s] = *(const short8*)(leafp[rt] + s * 32 + klane);
      }
    }

    // ---- wave 0: prefetch leaf c operands ----
    float cl[2][4], cr[2][4];
    int lsv[2][4], rsv[2][4];
    if (kq == 0){
      #pragma unroll
      for (int rt = 0; rt < 2; ++rt){
        int rbase = row0 + rt * 16 + ((lane >> 4) << 2);
        #pragma unroll
        for (int r = 0; r < 4; ++r){
          const int bb = rbase + r;
          const int ls = lsel[e * B_ + bb], rs = rsel[e * B_ + bb];
          lsv[rt][r] = ls; rsv[rt][r] = rs;
          int lc = ls & 0x3FF, rc = rs & 0x3FF;
          cl[rt][r] = (!(ls & PREVF_) && lc < 128) ? bf2f(leaf_c[((size_t)bb * T_ + lc) * H_ + colh]) : 0.0f;
          cr[rt][r] = (!(rs & PREVF_) && rc < 128) ? bf2f(leaf_c[((size_t)bb * T_ + rc) * H_ + colh]) : 0.0f;
        }
      }
    }

    // ---- wait: wave 0 gathers 32 distinct flag lines; S1 releases all ----
    if (kq == 0 && e > 0){
      const unsigned tgt = (unsigned)e;
      for (;;){
        unsigned v = __hip_atomic_load(pollptr, __ATOMIC_RELAXED, __HIP_MEMORY_SCOPE_AGENT);
        if (__all(v >= tgt)) break;
        __builtin_amdgcn_s_sleep(0);
      }
    }
    __syncthreads();   // S1: release; also LDS WAR guard for `part`

    // ---- node-child A loads (coherent, L3) ----
    #pragma unroll
    for (int rt = 0; rt < 2; ++rt){
      if (code[rt] >= 256 && code[rt] < 512){
        int row = row0 + rt * 16 + m16;
        const ushort_t* p = slot_h + ((size_t)row * SLH_ + (code[rt] - 256)) * H_ + kcolbase;
        #pragma unroll
        for (int s = 0; s < 8; ++s) Ab[rt][s] = load_a_coh(p + s * 32 + klane);
      }
    }

    // ---- wave 0: remaining c operands (PREVF regs / WG-private slot_c) ----
    if (kq == 0){
      #pragma unroll
      for (int rt = 0; rt < 2; ++rt){
        int rbase = row0 + rt * 16 + ((lane >> 4) << 2);
        #pragma unroll
        for (int r = 0; r < 4; ++r){
          const int bb = rbase + r;
          const int ls = lsv[rt][r], rs = rsv[rt][r];
          int lc = ls & 0x3FF, rc = rs & 0x3FF;
          if (ls & PREVF_) cl[rt][r] = creg[rt][r];
          else if (lc >= 256 && lc < 512) cl[rt][r] = slot_c[((size_t)bb * SLC_ + ((lc - 256) >> 1)) * H_ + colh];
          if (rs & PREVF_) cr[rt][r] = creg[rt][r];
          else if (rc >= 256 && rc < 512) cr[rt][r] = slot_c[((size_t)bb * SLC_ + ((rc - 256) >> 1)) * H_ + colh];
        }
      }
    }

    // ---- MFMA: B from pinned registers ----
    floatx4 acc[2][5];
    #pragma unroll
    for (int rt = 0; rt < 2; ++rt)
      #pragma unroll
      for (int g = 0; g < 5; ++g) acc[rt][g] = (floatx4){0,0,0,0};
    #pragma unroll
    for (int s = 0; s < 8; ++s){
      #pragma unroll
      for (int g = 0; g < 5; ++g){
        acc[0][g] = __builtin_amdgcn_mfma_f32_16x16x32_bf16(Ab[0][s], Wreg[g][s], acc[0][g], 0, 0, 0);
        acc[1][g] = __builtin_amdgcn_mfma_f32_16x16x32_bf16(Ab[1][s], Wreg[g][s], acc[1][g], 0, 0, 0);
      }
    }
    if (kq != 0){
      #pragma unroll
      for (int rt = 0; rt < 2; ++rt)
        #pragma unroll
        for (int g = 0; g < 5; ++g)
          part[kq - 1][rt][g][lane] = acc[rt][g];
    }
    __syncthreads();   // S2: partials visible to wave 0
    if (kq == 0){
      #pragma unroll
      for (int rt = 0; rt < 2; ++rt)
        #pragma unroll
        for (int g = 0; g < 5; ++g){
          floatx4 p0 = part[0][rt][g][lane];
          floatx4 p1 = part[1][rt][g][lane];
          floatx4 p2 = part[2][rt][g][lane];
          #pragma unroll
          for (int r = 0; r < 4; ++r) acc[rt][g][r] += p0[r] + p1[r] + p2[r];
        }
      #pragma unroll
      for (int rt = 0; rt < 2; ++rt){
        int rbase = row0 + rt * 16 + ((lane >> 4) << 2);
        #pragma unroll
        for (int r = 0; r < 4; ++r){
          const int bb = rbase + r;
          float cn = sigm(acc[rt][1][r] + bias[1]) * cl[rt][r]
                   + sigm(acc[rt][2][r] + bias[2]) * cr[rt][r]
                   + sigm(acc[rt][0][r] + bias[0]) * tanhf(acc[rt][3][r] + bias[3]);
          float hn = sigm(acc[rt][4][r] + bias[4]) * tanhf(cn);
          creg[rt][r] = cn;
          const int w = wph[e * B_ + bb];
          slot_c[((size_t)bb * SLC_ + (w >> 1)) * H_ + colh] = cn;   // WG-private
          store_h_coh(slot_h + ((size_t)bb * SLH_ + w) * H_ + colh, f2bf(hn));
        }
      }
      asm volatile("s_waitcnt vmcnt(0)" ::: "memory");   // drain h stores
      if (threadIdx.x == 0)
        __hip_atomic_store(myflag, (unsigned)(e + 1),
                           __ATOMIC_RELAXED, __HIP_MEMORY_SCOPE_AGENT);
    }
  }
}

// Final: out[b][j] = h of root (leaf / node slot / zeros). Covers every row.
__global__ __launch_bounds__(256) void final_kernel(const int* __restrict__ rootsel,
    const ushort_t* __restrict__ leaf_h, const ushort_t* __restrict__ slot_h,
    float* __restrict__ out){
  int i = blockIdx.x * 256 + threadIdx.x;
  if (i >= B_ * H_) return;
  int b = i >> 9, j = i & (H_ - 1);
  int code = rootsel[b] & 0x3FF;
  float v = 0.0f;
  if (code < 128)      v = bf2f(leaf_h[((size_t)b * T_ + code) * H_ + j]);
  else if (code < 512) v = bf2f(slot_h[((size_t)b * SLH_ + (code - 256)) * H_ + j]);
  out[i] = v;
}

extern "C" void kernel_launch(void* const* d_in, const int* in_sizes, int n_in,
                              void* d_out, int out_size, void* d_ws, size_t ws_size,
                              hipStream_t stream){
  const float* x        = (const float*)d_in[0];
  const float* W_proj   = (const float*)d_in[1];
  const float* b_proj   = (const float*)d_in[2];
  const float* W_gate   = (const float*)d_in[3];
  const float* b_gate   = (const float*)d_in[4];
  const float* W_reduce = (const float*)d_in[5];
  const float* b_reduce = (const float*)d_in[6];
  const int*   trans    = (const int*)d_in[7];
  float* out = (float*)d_out;

  char* ws = (char*)d_ws;
  size_t o = 0;
  ushort_t* WpP    = (ushort_t*)(ws + o); o += (size_t)32*10*64*8*2;    // 0.33 MB
  ushort_t* WgP    = (ushort_t*)(ws + o); o += (size_t)32*10*64*8*2;
  ushort_t* WrP    = (ushort_t*)(ws + o); o += (size_t)160*32*64*8*2;   // 5.24 MB
  ushort_t* leaf_h = (ushort_t*)(ws + o); o += (size_t)B_*T_*H_*2;      // 33.5 MB
  ushort_t* leaf_c = (ushort_t*)(ws + o); o += (size_t)B_*T_*H_*2;      // 33.5 MB
  ushort_t* slot_h = (ushort_t*)(ws + o); o += (size_t)B_*SLH_*H_*2;    // 68.2 MB
  float*    slot_c = (float*)(ws + o);    o += (size_t)B_*SLC_*H_*4;    // 68.2 MB
  int* lsel    = (int*)(ws + o); o += (size_t)NE_*B_*4;
  int* rsel    = (int*)(ws + o); o += (size_t)NE_*B_*4;
  int* wph     = (int*)(ws + o); o += (size_t)NE_*B_*4;
  int* rootsel = (int*)(ws + o); o += (size_t)B_*4;
  unsigned* gflags = (unsigned*)(ws + o); o += (size_t)8 * 32 * 128;  // 1 line per (rg,cth)
  ushort_t* zbuf = (ushort_t*)(ws + o); o += 2048;
  // xb (bf16 x, padded to K=320, 21 MB) overlays slot_c: xb is only read
  // before chain_kernel; slot_c is only accessed during/after it.
  ushort_t* xb = (ushort_t*)slot_c;
  (void)ws_size; (void)in_sizes; (void)n_in; (void)out_size;

  hipMemsetAsync(gflags, 0, (size_t)8 * 32 * 128, stream);
  hipMemsetAsync(zbuf, 0, 2048, stream);
  xcast_kernel<<<((B_*T_)*40 + 255)/256, 256, 0, stream>>>(x, xb);
  pack_w_kernel<<<(32*10*64 + 255)/256, 256, 0, stream>>>(W_proj, WpP, 300, 512, 10, 32*10*64);
  pack_w_kernel<<<(32*10*64 + 255)/256, 256, 0, stream>>>(W_gate, WgP, 300, 512, 10, 32*10*64);
  pack_w_kernel<<<(160*32*64 + 255)/256, 256, 0, stream>>>(W_reduce, WrP, 1024, 2560, 32, 160*32*64);
  sched_kernel<<<8, 32, 0, stream>>>(trans, lsel, rsel, wph, rootsel);
  leaf_kernel<<<dim3(512, 4), 256, 0, stream>>>(xb, WpP, WgP, b_proj, b_gate, leaf_h, leaf_c);
  chain_kernel<<<256, 256, 0, stream>>>(WrP, b_reduce, leaf_h, leaf_c, slot_h, slot_c,
                                        lsel, rsel, wph, zbuf, gflags);
  final_kernel<<<(B_*H_ + 255)/256, 256, 0, stream>>>(rootsel, leaf_h, slot_h, out);
}